// Round 2
// baseline (74.210 us; speedup 1.0000x reference)
//
#include <hip/hip_runtime.h>
#include <math.h>

#define NFEAT 16
#define NRULE 64
#define NCHUNK 19   // float4-chunks per lane: 4xB1,4xB2,4xR1,4xR2,P,KL,bias
#define IT 4        // sample-tiles per wave (16 samples each)

typedef _Float16 half8 __attribute__((ext_vector_type(8)));
typedef float    f4    __attribute__((ext_vector_type(4)));
union F4H8 { float4 f; half8 h; };
union F4A  { float4 v; float f[4]; };

// ---------------------------------------------------------------------------
// Single fused kernel — NO workspace use (the harness's 256 MiB workspace
// re-poison fill was ~40.5 µs of the timed region; going workspace-free is
// the only way to evict it).
//
// Per-block prologue (256 threads, identical arithmetic to the old
// fuzzy_prep -> bitwise-identical results): build the MFMA B-operand
// fragment table in LDS.
//   LDS float4 chunk c, lane L at sh4[c*64 + L]:
//     c = T      : B1=[Bh;Bh] frag, tile T      c = 4+T  : B2=[Bl;Bl]
//     c = 8+T    : R1=[Rh;Rh]                   c = 12+T : R2=[Rl;Rl]
//     c = 16/17/18 : P[4] / KL[4] / bias[4] (element T)
// B-frag lane layout: n = lane&15 (rule in tile), k = quad*8+j.
// K=32 packs the f16 split: A = [Xh | Xl]; B1 = [Wh;Wh]; B2 = [Wl;Wl]
//   => mfma(A,B1)+mfma(A,B2) = Xh*Wh + Xl*Wh + Xh*Wl + Xl*Wl.
// Bw = 2*inv*mu*log2e ; P = -inv*log2e ; KL = -log2e*sum inv*mu^2.
//
// Main phase: each wave, IT tiles of 16 samples, all 64 rules via
// 4 N-tiles x 4 mfma.  A-frag: lane = (m=lane&15 sample, k=quad*8+j);
// quads 0,1 = Xh, 2,3 = Xl.  C/D: col = lane&15 (rule), row = quad*4+reg.
// ---------------------------------------------------------------------------
__global__ __launch_bounds__(256, 2) void fuzzy_all(const float* __restrict__ x,
                                                    const float* __restrict__ mu,
                                                    const float* __restrict__ sigma,
                                                    const float* __restrict__ rho,
                                                    float* __restrict__ out, int n) {
    const float L2E = 1.4426950408889634f;
    __shared__ float4 sh4[NCHUNK * 64];
    __shared__ int u_sh[256];
    __shared__ float flag_sh;

    const int t    = threadIdx.x;
    const int L    = t & 63;
    const int T    = t >> 6;          // wave id == rule-tile this thread preps
    const int m    = L & 15;
    const int quad = L >> 4;
    const int rule = T * 16 + m;
    const int fb   = (quad & 1) * 8;  // feats this lane's k-slots map to

    // ---- prologue: build frag table in LDS (same math as old fuzzy_prep) ----
    {
        F4A M[4], S[4];
        const float4* mup = (const float4*)(mu + rule * NFEAT);
        const float4* sgp = (const float4*)(sigma + rule * NFEAT);
#pragma unroll
        for (int i = 0; i < 4; ++i) { M[i].v = mup[i]; S[i].v = sgp[i]; }

        F4H8 b1, b2, r1, r2;
#pragma unroll
        for (int j = 0; j < 8; ++j) {
            int f = fb + j;
            float mm = M[f >> 2].f[f & 3];
            float ss = S[f >> 2].f[f & 3];
            float inv = 1.0f / (2.0f * ss * ss);
            float Bw = 2.0f * inv * mm * L2E;
            _Float16 bh = (_Float16)Bw;
            b1.h[j] = bh;
            b2.h[j] = (_Float16)(Bw - (float)bh);
            float Rw = rho[rule * (NFEAT + 1) + f];
            _Float16 rh = (_Float16)Rw;
            r1.h[j] = rh;
            r2.h[j] = (_Float16)(Rw - (float)rh);
        }
        sh4[(0  + T) * 64 + L] = b1.f;
        sh4[(4  + T) * 64 + L] = b2.f;
        sh4[(8  + T) * 64 + L] = r1.f;
        sh4[(12 + T) * 64 + L] = r2.f;

        float s0 = S[0].f[0];
        float c0 = 1.0f / (2.0f * s0 * s0);
        float K = 0.0f;
        int u = 1;
#pragma unroll
        for (int a = 0; a < NFEAT; ++a) {
            float mm = M[a >> 2].f[a & 3];
            float ss = S[a >> 2].f[a & 3];
            float inv = 1.0f / (2.0f * ss * ss);
            if (inv != c0) u = 0;
            K = fmaf(-inv * mm, mm, K);
        }
        float* shf = (float*)sh4;
        shf[(16 * 64 + L) * 4 + T] = -c0 * L2E;                       // P
        shf[(17 * 64 + L) * 4 + T] = K * L2E;                         // KL
        shf[(18 * 64 + L) * 4 + T] = rho[rule * (NFEAT + 1) + NFEAT]; // bias

        u_sh[t] = u;
    }
    __syncthreads();
    if (t < 64) {
        int uu = u_sh[t] & u_sh[t + 64] & u_sh[t + 128] & u_sh[t + 192];
        unsigned long long b = __ballot(uu != 0);
        if (t == 0) flag_sh = (b == ~0ull) ? 1.0f : 0.0f;
    }
    __syncthreads();

    const int wv   = __builtin_amdgcn_readfirstlane(T);
    const int flag = __builtin_amdgcn_readfirstlane((int)flag_sh);

    if (flag) {
        // frag load from LDS (16 B lane stride -> conflict-free ds_read_b128)
        F4H8 b1[4], b2[4], r1[4], r2[4];
#pragma unroll
        for (int Tt = 0; Tt < 4; ++Tt) {
            b1[Tt].f = sh4[(0  + Tt) * 64 + L];
            b2[Tt].f = sh4[(4  + Tt) * 64 + L];
            r1[Tt].f = sh4[(8  + Tt) * 64 + L];
            r2[Tt].f = sh4[(12 + Tt) * 64 + L];
        }
        float4 Pq = sh4[16 * 64 + L], Kq = sh4[17 * 64 + L], Bq = sh4[18 * 64 + L];
        float PvA[4]  = {Pq.x, Pq.y, Pq.z, Pq.w};
        float KLvA[4] = {Kq.x, Kq.y, Kq.z, Kq.w};
        float BvA[4]  = {Bq.x, Bq.y, Bq.z, Bq.w};

#pragma unroll
        for (int it = 0; it < IT; ++it) {
            int gt = (blockIdx.x * 4 + wv) * IT + it;
            int tb = gt * 16;
            if (tb >= n) break;
            const float4* xp = (const float4*)(x + (size_t)(tb + m) * NFEAT + fb);
            float4 xa = xp[0], xb = xp[1];
            float xv[8] = {xa.x, xa.y, xa.z, xa.w, xb.x, xb.y, xb.z, xb.w};
            F4H8 af;
            float qp = 0.0f;
#pragma unroll
            for (int j = 0; j < 8; ++j) {
                _Float16 h = (_Float16)xv[j];
                af.h[j] = (quad < 2) ? h : (_Float16)(xv[j] - (float)h);
                qp = fmaf(xv[j], xv[j], qp);
            }
            float Qf = qp + __shfl_xor(qp, 16);   // Q[sample m], all lanes
            float Qr[4];
#pragma unroll
            for (int p = 0; p < 4; ++p) Qr[p] = __shfl(Qf, quad * 4 + p);

            f4 nsum = {0.f, 0.f, 0.f, 0.f}, dsum = {0.f, 0.f, 0.f, 0.f};
#pragma unroll
            for (int Tt = 0; Tt < 4; ++Tt) {
                f4 z4 = {0.f, 0.f, 0.f, 0.f};
                f4 accL = __builtin_amdgcn_mfma_f32_16x16x32_f16(af.h, b1[Tt].h, z4, 0, 0, 0);
                accL    = __builtin_amdgcn_mfma_f32_16x16x32_f16(af.h, b2[Tt].h, accL, 0, 0, 0);
                f4 accZ = __builtin_amdgcn_mfma_f32_16x16x32_f16(af.h, r1[Tt].h, z4, 0, 0, 0);
                accZ    = __builtin_amdgcn_mfma_f32_16x16x32_f16(af.h, r2[Tt].h, accZ, 0, 0, 0);
#pragma unroll
                for (int p = 0; p < 4; ++p) {
                    float l = fmaf(PvA[Tt], Qr[p], accL[p] + KLvA[Tt]);
                    float w = __builtin_amdgcn_exp2f(l);
                    float zf = accZ[p] + BvA[Tt];
                    nsum[p] = fmaf(zf, w, nsum[p]);
                    dsum[p] += w;
                }
            }
            // reduce over the 16 rule-columns (lanes differing in low 4 bits)
#pragma unroll
            for (int d = 1; d < 16; d <<= 1) {
#pragma unroll
                for (int p = 0; p < 4; ++p) {
                    nsum[p] += __shfl_xor(nsum[p], d);
                    dsum[p] += __shfl_xor(dsum[p], d);
                }
            }
            if ((L & 15) == 0) {   // 4 writer lanes; rows quad*4+p
                float4 o;
                o.x = nsum[0] * __builtin_amdgcn_rcpf(dsum[0] + 1e-13f);
                o.y = nsum[1] * __builtin_amdgcn_rcpf(dsum[1] + 1e-13f);
                o.z = nsum[2] * __builtin_amdgcn_rcpf(dsum[2] + 1e-13f);
                o.w = nsum[3] * __builtin_amdgcn_rcpf(dsum[3] + 1e-13f);
                ((float4*)(out + tb))[quad] = o;
            }
        }
    } else {
        // General fallback (arbitrary sigma; never taken for this input).
#pragma unroll
        for (int it = 0; it < IT; ++it) {
            int gt = (blockIdx.x * 4 + wv) * IT + it;
            int tb = gt * 16;
            if (tb >= n) break;
            int s = tb + m;
            const float4* xp = (const float4*)(x + (size_t)s * NFEAT);
            float4 a = xp[0], b = xp[1], c = xp[2], d = xp[3];
            float xs[NFEAT] = {a.x,a.y,a.z,a.w, b.x,b.y,b.z,b.w,
                               c.x,c.y,c.z,c.w, d.x,d.y,d.z,d.w};
            float num = 0.0f, den = 0.0f;
            for (int r = quad * 16; r < quad * 16 + 16; ++r) {
                float z = rho[r * (NFEAT + 1) + NFEAT];
                float l = 0.0f;
                for (int aa = 0; aa < NFEAT; ++aa) {
                    float mm = mu[r * NFEAT + aa];
                    float ss = sigma[r * NFEAT + aa];
                    float inv = 1.0f / (2.0f * ss * ss);
                    float dd = xs[aa] - mm;
                    l = fmaf(-inv * dd, dd, l);
                    z = fmaf(rho[r * (NFEAT + 1) + aa], xs[aa], z);
                }
                float w = __builtin_amdgcn_exp2f(l * L2E);
                num = fmaf(z, w, num);
                den += w;
            }
            num += __shfl_xor(num, 16); den += __shfl_xor(den, 16);
            num += __shfl_xor(num, 32); den += __shfl_xor(den, 32);
            if (L < 16) out[tb + L] = num / (den + 1e-13f);
        }
    }
}

extern "C" void kernel_launch(void* const* d_in, const int* in_sizes, int n_in,
                              void* d_out, int out_size, void* d_ws, size_t ws_size,
                              hipStream_t stream) {
    const float* x     = (const float*)d_in[0];   // [N,16]
    const float* mu    = (const float*)d_in[1];   // [64,16]
    const float* sigma = (const float*)d_in[2];   // [64,16]
    const float* rho   = (const float*)d_in[3];   // [64,17]
    float* out = (float*)d_out;
    (void)d_ws; (void)ws_size;                    // workspace-free on purpose

    int n = in_sizes[0] / NFEAT;                  // 131072
    int samples_per_block = 4 * IT * 16;          // 4 waves x IT tiles x 16
    int blocks = (n + samples_per_block - 1) / samples_per_block;  // 512
    fuzzy_all<<<blocks, 256, 0, stream>>>(x, mu, sigma, rho, out, n);
}

// Round 3
// 70.211 us; speedup vs baseline: 1.0570x; 1.0570x over previous
//
#include <hip/hip_runtime.h>
#include <math.h>

#define NFEAT 16
#define NRULE 64
#define NCHUNK 19               // float4-chunks per lane: 4xB1,4xB2,4xR1,4xR2,P,KL,bias
#define FLAG_DW (NCHUNK * 64 * 4)  // sigma-uniform flag slot (table end)

typedef _Float16 half8 __attribute__((ext_vector_type(8)));
typedef float    f4    __attribute__((ext_vector_type(4)));
union F4H8 { float4 f; half8 h; };
union F4A  { float4 v; float f[4]; };

// ---------------------------------------------------------------------------
// Prep: build per-lane MFMA B-operand fragment table in d_ws.
// Chunk-major layout (coalesced for main): float4 chunk c, lane L at
// t4[c*64 + L]. c=T: B1; 4+T: B2; 8+T: R1; 12+T: R2; 16/17/18: P/KL/bias.
// B-frag lane layout: n = lane&15 (rule within tile), k = quad*8+j.
// K=32 packs the f16 split: A = [Xh | Xl]; B1 = [Wh;Wh]; B2 = [Wl;Wl]
//   => mfma(A,B1) + mfma(A,B2) = Xh*Wh + Xl*Wh + Xh*Wl + Xl*Wl.
// Bw = 2*inv*mu*log2e ; P = -inv*log2e ; KL = -log2e*sum inv*mu^2.
// ---------------------------------------------------------------------------
__global__ void fuzzy_prep(const float* __restrict__ mu,
                           const float* __restrict__ sigma,
                           const float* __restrict__ rho,
                           float* __restrict__ tab) {
    const float L2E = 1.4426950408889634f;
    __shared__ int u_sh[256];
    int t = threadIdx.x;
    int L = t & 63, T = t >> 6;
    int n = L & 15, quad = L >> 4;
    int rule = T * 16 + n;
    int fb = (quad & 1) * 8;      // feats this lane's k-slots map to

    F4A M[4], S[4];
    const float4* mup = (const float4*)(mu + rule * NFEAT);
    const float4* sgp = (const float4*)(sigma + rule * NFEAT);
#pragma unroll
    for (int i = 0; i < 4; ++i) { M[i].v = mup[i]; S[i].v = sgp[i]; }

    F4H8 b1, b2, r1, r2;
#pragma unroll
    for (int j = 0; j < 8; ++j) {
        int f = fb + j;
        float m = M[f >> 2].f[f & 3];
        float s = S[f >> 2].f[f & 3];
        float inv = 1.0f / (2.0f * s * s);
        float Bw = 2.0f * inv * m * L2E;
        _Float16 bh = (_Float16)Bw;
        b1.h[j] = bh;
        b2.h[j] = (_Float16)(Bw - (float)bh);
        float Rw = rho[rule * (NFEAT + 1) + f];
        _Float16 rh = (_Float16)Rw;
        r1.h[j] = rh;
        r2.h[j] = (_Float16)(Rw - (float)rh);
    }
    float4* t4 = (float4*)tab;
    t4[(0  + T) * 64 + L] = b1.f;
    t4[(4  + T) * 64 + L] = b2.f;
    t4[(8  + T) * 64 + L] = r1.f;
    t4[(12 + T) * 64 + L] = r2.f;

    float s0 = S[0].f[0];
    float c0 = 1.0f / (2.0f * s0 * s0);
    float K = 0.0f;
    int u = 1;
#pragma unroll
    for (int a = 0; a < NFEAT; ++a) {
        float m = M[a >> 2].f[a & 3];
        float s = S[a >> 2].f[a & 3];
        float inv = 1.0f / (2.0f * s * s);
        if (inv != c0) u = 0;
        K = fmaf(-inv * m, m, K);
    }
    tab[(16 * 64 + L) * 4 + T] = -c0 * L2E;                      // P
    tab[(17 * 64 + L) * 4 + T] = K * L2E;                        // KL
    tab[(18 * 64 + L) * 4 + T] = rho[rule * (NFEAT + 1) + NFEAT]; // bias

    u_sh[t] = u;
    __syncthreads();
    if (t < 64) {
        int uu = u_sh[t] & u_sh[t + 64] & u_sh[t + 128] & u_sh[t + 192];
        unsigned long long b = __ballot(uu != 0);
        if (t == 0) tab[FLAG_DW] = (b == ~0ull) ? 1.0f : 0.0f;
    }
}

// ---------------------------------------------------------------------------
// Main: 1024 blocks x 256 thr; each wave is self-contained (no LDS, no sync):
// 2 tiles of 16 samples, all 64 rules via 4 N-tiles x 4 mfma each.
// Fragment loads are chunk-major: t4[c*64 + L] -> each of the 19 loads is
// one fully-coalesced 1-KB wave read.
// A-frag: lane = (m = lane&15 sample, k = quad*8+j); quads 0,1 = Xh, 2,3 = Xl.
// C/D: col = lane&15 (rule), row = quad*4+reg (sample)  [m89-verified mapping]
// ---------------------------------------------------------------------------
__global__ __launch_bounds__(256, 4) void fuzzy_main(const float* __restrict__ x,
                                                     const float* __restrict__ tab,
                                                     const float* __restrict__ mu,
                                                     const float* __restrict__ sigma,
                                                     const float* __restrict__ rho,
                                                     float* __restrict__ out, int n) {
    const int tid  = threadIdx.x;
    const int L    = tid & 63;
    const int quad = L >> 4;
    const int wv   = __builtin_amdgcn_readfirstlane(tid >> 6);
    const int flag = __builtin_amdgcn_readfirstlane((int)tab[FLAG_DW]);
    const int m    = L & 15;
    const int fb   = (quad & 1) * 8;

    if (flag) {
        const float4* t4 = (const float4*)tab;
        F4H8 b1[4], b2[4], r1[4], r2[4];
#pragma unroll
        for (int T = 0; T < 4; ++T) {
            b1[T].f = t4[(0  + T) * 64 + L];
            b2[T].f = t4[(4  + T) * 64 + L];
            r1[T].f = t4[(8  + T) * 64 + L];
            r2[T].f = t4[(12 + T) * 64 + L];
        }
        float4 Pq = t4[16 * 64 + L], Kq = t4[17 * 64 + L], Bq = t4[18 * 64 + L];
        float PvA[4]  = {Pq.x, Pq.y, Pq.z, Pq.w};
        float KLvA[4] = {Kq.x, Kq.y, Kq.z, Kq.w};
        float BvA[4]  = {Bq.x, Bq.y, Bq.z, Bq.w};

#pragma unroll
        for (int it = 0; it < 2; ++it) {
            int gt = (blockIdx.x * 4 + wv) * 2 + it;
            int tb = gt * 16;
            if (tb >= n) break;
            const float4* xp = (const float4*)(x + (size_t)(tb + m) * NFEAT + fb);
            float4 xa = xp[0], xb = xp[1];
            float xv[8] = {xa.x, xa.y, xa.z, xa.w, xb.x, xb.y, xb.z, xb.w};
            F4H8 af;
            float qp = 0.0f;
#pragma unroll
            for (int j = 0; j < 8; ++j) {
                _Float16 h = (_Float16)xv[j];
                af.h[j] = (quad < 2) ? h : (_Float16)(xv[j] - (float)h);
                qp = fmaf(xv[j], xv[j], qp);
            }
            float Qf = qp + __shfl_xor(qp, 16);   // Q[sample m], all lanes
            float Qr[4];
#pragma unroll
            for (int p = 0; p < 4; ++p) Qr[p] = __shfl(Qf, quad * 4 + p);

            f4 nsum = {0.f, 0.f, 0.f, 0.f}, dsum = {0.f, 0.f, 0.f, 0.f};
#pragma unroll
            for (int T = 0; T < 4; ++T) {
                f4 z4 = {0.f, 0.f, 0.f, 0.f};
                f4 accL = __builtin_amdgcn_mfma_f32_16x16x32_f16(af.h, b1[T].h, z4, 0, 0, 0);
                accL    = __builtin_amdgcn_mfma_f32_16x16x32_f16(af.h, b2[T].h, accL, 0, 0, 0);
                f4 accZ = __builtin_amdgcn_mfma_f32_16x16x32_f16(af.h, r1[T].h, z4, 0, 0, 0);
                accZ    = __builtin_amdgcn_mfma_f32_16x16x32_f16(af.h, r2[T].h, accZ, 0, 0, 0);
#pragma unroll
                for (int p = 0; p < 4; ++p) {
                    float l = fmaf(PvA[T], Qr[p], accL[p] + KLvA[T]);
                    float w = __builtin_amdgcn_exp2f(l);
                    float zf = accZ[p] + BvA[T];
                    nsum[p] = fmaf(zf, w, nsum[p]);
                    dsum[p] += w;
                }
            }
            // reduce over the 16 rule-columns (lanes differing in low 4 bits)
#pragma unroll
            for (int d = 1; d < 16; d <<= 1) {
#pragma unroll
                for (int p = 0; p < 4; ++p) {
                    nsum[p] += __shfl_xor(nsum[p], d);
                    dsum[p] += __shfl_xor(dsum[p], d);
                }
            }
            if ((L & 15) == 0) {   // 4 writer lanes; rows quad*4+p
                float4 o;
                o.x = nsum[0] * __builtin_amdgcn_rcpf(dsum[0] + 1e-13f);
                o.y = nsum[1] * __builtin_amdgcn_rcpf(dsum[1] + 1e-13f);
                o.z = nsum[2] * __builtin_amdgcn_rcpf(dsum[2] + 1e-13f);
                o.w = nsum[3] * __builtin_amdgcn_rcpf(dsum[3] + 1e-13f);
                ((float4*)(out + tb))[quad] = o;
            }
        }
    } else {
        // General fallback (arbitrary sigma; never taken for this input).
        const float L2E = 1.4426950408889634f;
#pragma unroll
        for (int it = 0; it < 2; ++it) {
            int gt = (blockIdx.x * 4 + wv) * 2 + it;
            int tb = gt * 16;
            if (tb >= n) break;
            int s = tb + m;
            const float4* xp = (const float4*)(x + (size_t)s * NFEAT);
            float4 a = xp[0], b = xp[1], c = xp[2], d = xp[3];
            float xs[NFEAT] = {a.x,a.y,a.z,a.w, b.x,b.y,b.z,b.w,
                               c.x,c.y,c.z,c.w, d.x,d.y,d.z,d.w};
            float num = 0.0f, den = 0.0f;
            for (int r = quad * 16; r < quad * 16 + 16; ++r) {
                float z = rho[r * (NFEAT + 1) + NFEAT];
                float l = 0.0f;
                for (int aa = 0; aa < NFEAT; ++aa) {
                    float mm = mu[r * NFEAT + aa];
                    float ss = sigma[r * NFEAT + aa];
                    float inv = 1.0f / (2.0f * ss * ss);
                    float dd = xs[aa] - mm;
                    l = fmaf(-inv * dd, dd, l);
                    z = fmaf(rho[r * (NFEAT + 1) + aa], xs[aa], z);
                }
                float w = __builtin_amdgcn_exp2f(l * L2E);
                num = fmaf(z, w, num);
                den += w;
            }
            num += __shfl_xor(num, 16); den += __shfl_xor(den, 16);
            num += __shfl_xor(num, 32); den += __shfl_xor(den, 32);
            if (L < 16) out[tb + L] = num / (den + 1e-13f);
        }
    }
}

extern "C" void kernel_launch(void* const* d_in, const int* in_sizes, int n_in,
                              void* d_out, int out_size, void* d_ws, size_t ws_size,
                              hipStream_t stream) {
    const float* x     = (const float*)d_in[0];   // [N,16]
    const float* mu    = (const float*)d_in[1];   // [64,16]
    const float* sigma = (const float*)d_in[2];   // [64,16]
    const float* rho   = (const float*)d_in[3];   // [64,17]
    float* out = (float*)d_out;
    float* tab = (float*)d_ws;                    // 4865 dwords used

    int n = in_sizes[0] / NFEAT;                  // 131072

    fuzzy_prep<<<1, 256, 0, stream>>>(mu, sigma, rho, tab);
    int blocks = (n + 127) / 128;                 // 4 waves x 2 tiles x 16 samples
    fuzzy_main<<<blocks, 256, 0, stream>>>(x, tab, mu, sigma, rho, out, n);
}